// Round 10
// baseline (603.660 us; speedup 1.0000x reference)
//
#include <hip/hip_runtime.h>
#include <math.h>

#define BATCH 4096
#define IN_DIM 1024
#define UNITS 2048
#define OUT_DIM 1000
#define NPAD_OUT 1024
#define NITER 3

typedef __bf16 bf16_t;
typedef __attribute__((ext_vector_type(8))) __bf16 bfrag;
typedef __attribute__((ext_vector_type(4))) float f32x4;

typedef __attribute__((address_space(1))) void gvoid_t;
typedef __attribute__((address_space(3))) void lvoid_t;

__device__ __forceinline__ void gld_lds16(const void* g, void* l) {
  __builtin_amdgcn_global_load_lds((gvoid_t*)g, (lvoid_t*)l, 16, 0, 0);
}

// fast tanh: 1 - 2/(exp2(2*log2e*x)+1); v_exp_f32+v_rcp_f32, ~1ulp f32 (bf16-irrelevant)
__device__ __forceinline__ float fast_tanh(float x) {
  float e, r;
  asm("v_exp_f32 %0, %1" : "=v"(e) : "v"(x * 2.88539008177793f));
  asm("v_rcp_f32 %0, %1" : "=v"(r) : "v"(e + 1.0f));
  return __builtin_fmaf(-2.0f, r, 1.0f);
}

// ---------------- elementwise f32 -> bf16 ----------------
__global__ void k_f32_to_bf16(const float* __restrict__ in, bf16_t* __restrict__ out, int n) {
  int i = blockIdx.x * 256 + threadIdx.x;
  if (i < n) out[i] = (bf16_t)in[i];
}

// ---- transpose f32 (K x N, row stride N) -> bf16 (Npad x K); pads with 0 ----
__global__ void k_transpose_bf16(const float* __restrict__ src, bf16_t* __restrict__ dst,
                                 int K, int N, int Npad) {
  __shared__ float t[32][33];
  int n0 = blockIdx.x * 32;
  int k0 = blockIdx.y * 32;
  int tx = threadIdx.x, ty = threadIdx.y;  // 32 x 8
#pragma unroll
  for (int i = 0; i < 4; i++) {
    int k = k0 + ty + i * 8;
    int n = n0 + tx;
    t[ty + i * 8][tx] = (n < N) ? src[(size_t)k * N + n] : 0.0f;
  }
  __syncthreads();
#pragma unroll
  for (int i = 0; i < 4; i++) {
    int n = n0 + ty + i * 8;
    int k = k0 + tx;
    if (n < Npad) dst[(size_t)n * K + k] = (bf16_t)t[tx][ty + i * 8];
  }
}

// ======== 128^2 4-wave GEMM, double-buffered LDS + counted vmcnt + 1 barrier/K-step ========
// 64KB LDS -> 2 blocks/CU (grid gives exactly 2/CU); cross-block TLP + 1-ahead prefetch.
// Hazard scheme (proven rounds 7-8): per iter t: vmcnt(8) [tile t's own 8 loads done,
// t+1's 8 in flight], s_barrier [all waves' stores visible; all iter t-1 reads done],
// then stage tile t+1 into buf[cur^1] (its readers finished before THIS barrier).
// MODE 0: Ob = bf16(acc + bias)
// MODE 1: Ob = bf16( (f32)Uin + 0.1*tanh(acc + bias) )   (all state bf16)
// MODE 3: Of = acc + bias, only cols < Nvalid (f32 logits)
template <int MODE>
__launch_bounds__(256, 2)
__global__ void k_gemm128(const bf16_t* __restrict__ A, const bf16_t* __restrict__ Bt,
                          const float* __restrict__ bias, const bf16_t* __restrict__ Uin,
                          bf16_t* __restrict__ Ob, float* __restrict__ Of,
                          int M, int N, int K, int Nvalid) {
  __shared__ bf16_t As2[2][128 * 64];  // 32 KiB
  __shared__ bf16_t Bs2[2][128 * 64];  // 32 KiB

  const int tid = threadIdx.x;
  const int lane = tid & 63;
  const int wid = tid >> 6;

  // XCD-aware bijective swizzle (grid % 8 == 0 for all our launches)
  int bid = (int)blockIdx.x;
  const int cpx = (int)gridDim.x >> 3;
  bid = (bid & 7) * cpx + (bid >> 3);
  const int nbx = N >> 7;
  const int bn0 = (bid % nbx) * 128;
  const int bm0 = (bid / nbx) * 128;

  const int srow = lane >> 3;
  const int sslot = (lane & 7) ^ srow;  // XOR swizzle via pre-swizzled global source
  const int frow = lane & 15;
  const int fk = lane >> 4;

  f32x4 acc[4][4];
#pragma unroll
  for (int m = 0; m < 4; m++)
#pragma unroll
    for (int n = 0; n < 4; n++) acc[m][n] = (f32x4){0.f, 0.f, 0.f, 0.f};

  const int wm = wid >> 1;
  const int wn = wid & 1;

  const size_t aRowBase = (size_t)(bm0 + wid * 32 + srow) * K + (size_t)sslot * 8;
  const size_t bRowBase = (size_t)(bn0 + wid * 32 + srow) * K + (size_t)sslot * 8;

  auto stageTile = [&](int buf, int kt) {
#pragma unroll
    for (int i = 0; i < 4; i++) {
      gld_lds16(A + aRowBase + (size_t)i * 8 * K + kt,
                (char*)&As2[buf][0] + (wid * 4 + i) * 1024);
      gld_lds16(Bt + bRowBase + (size_t)i * 8 * K + kt,
                (char*)&Bs2[buf][0] + (wid * 4 + i) * 1024);
    }
  };

  const int NT = K >> 6;
  stageTile(0, 0);  // prologue: 8 loads in flight

  int cur = 0;
  for (int t = 0; t < NT; ++t) {
    // drain own 8 oldest (tile t); tile t+1's 8 stay in flight across the barrier
    if (t + 1 < NT) {
      asm volatile("s_waitcnt vmcnt(8)" ::: "memory");
    } else {
      asm volatile("s_waitcnt vmcnt(0)" ::: "memory");
    }
    __builtin_amdgcn_s_barrier();
    if (t + 1 < NT) stageTile(cur ^ 1, (t + 1) << 6);

#pragma unroll
    for (int s = 0; s < 2; s++) {
      bfrag af[4], bq[4];
#pragma unroll
      for (int m = 0; m < 4; m++) {
        int row = wm * 64 + m * 16 + frow;
        int slot = (s * 4 + fk) ^ (row & 7);
        af[m] = *reinterpret_cast<const bfrag*>((const char*)&As2[cur][0] + row * 128 + slot * 16);
      }
#pragma unroll
      for (int n = 0; n < 4; n++) {
        int row = wn * 64 + n * 16 + frow;
        int slot = (s * 4 + fk) ^ (row & 7);
        bq[n] = *reinterpret_cast<const bfrag*>((const char*)&Bs2[cur][0] + row * 128 + slot * 16);
      }
      __builtin_amdgcn_s_setprio(1);
#pragma unroll
      for (int m = 0; m < 4; m++)
#pragma unroll
        for (int n = 0; n < 4; n++)
          acc[m][n] = __builtin_amdgcn_mfma_f32_16x16x32_bf16(af[m], bq[n], acc[m][n], 0, 0, 0);
      __builtin_amdgcn_s_setprio(0);
    }
    cur ^= 1;
  }

  // epilogue: C/D layout col = lane&15 (-> gn), row = (lane>>4)*4 + j (-> gm)
#pragma unroll
  for (int m = 0; m < 4; m++) {
#pragma unroll
    for (int n = 0; n < 4; n++) {
      const int gn = bn0 + wn * 64 + n * 16 + frow;
#pragma unroll
      for (int j = 0; j < 4; j++) {
        const int gm = bm0 + wm * 64 + m * 16 + fk * 4 + j;
        const size_t off = (size_t)gm * N + gn;
        float v = acc[m][n][j];
        if (MODE == 0) {
          Ob[off] = (bf16_t)(v + bias[gn]);
        } else if (MODE == 1) {
          v = (float)Uin[off] + 0.1f * fast_tanh(v + bias[gn]);
          Ob[off] = (bf16_t)v;
        } else {  // MODE 3
          if (gn < Nvalid) Of[off] = v + bias[gn];
        }
      }
    }
  }
}

// ---------------- row softmax ----------------
__global__ void k_softmax(const float* __restrict__ logits, float* __restrict__ out) {
  __shared__ float red[256];
  const int r = blockIdx.x;
  const float* L = logits + (size_t)r * NPAD_OUT;
  float* O = out + (size_t)r * OUT_DIM;
  const int tid = threadIdx.x;

  float lmax = -INFINITY;
  for (int j = tid; j < OUT_DIM; j += 256) lmax = fmaxf(lmax, L[j]);
  red[tid] = lmax;
  __syncthreads();
  for (int s = 128; s > 0; s >>= 1) {
    if (tid < s) red[tid] = fmaxf(red[tid], red[tid + s]);
    __syncthreads();
  }
  const float rmax = red[0];
  __syncthreads();
  float lsum = 0.f;
  for (int j = tid; j < OUT_DIM; j += 256) {
    float e = expf(L[j] - rmax);
    O[j] = e;
    lsum += e;
  }
  red[tid] = lsum;
  __syncthreads();
  for (int s = 128; s > 0; s >>= 1) {
    if (tid < s) red[tid] += red[tid + s];
    __syncthreads();
  }
  const float inv = 1.0f / red[0];
  for (int j = tid; j < OUT_DIM; j += 256) O[j] *= inv;
}

extern "C" void kernel_launch(void* const* d_in, const int* in_sizes, int n_in,
                              void* d_out, int out_size, void* d_ws, size_t ws_size,
                              hipStream_t stream) {
  const float* x = (const float*)d_in[0];
  const float* W_in = (const float*)d_in[1];
  const float* b_in = (const float*)d_in[2];
  const float* W_out = (const float*)d_in[3];
  const float* b_out = (const float*)d_in[4];
  const float* W[4] = {(const float*)d_in[5], (const float*)d_in[7],
                       (const float*)d_in[9], (const float*)d_in[11]};
  const float* bb[4] = {(const float*)d_in[6], (const float*)d_in[8],
                        (const float*)d_in[10], (const float*)d_in[12]};
  float* out = (float*)d_out;

  // ---- workspace: 3x16 + 8 + 16 = 72 MiB (proven-safe footprint) ----
  char* ws = (char*)d_ws;
  size_t off = 0;
  auto alloc = [&](size_t bytes) {
    void* p = ws + off;
    off += (bytes + 255) & ~(size_t)255;
    return p;
  };
  bf16_t* B0 = (bf16_t*)alloc((size_t)BATCH * UNITS * 2);
  bf16_t* B1 = (bf16_t*)alloc((size_t)BATCH * UNITS * 2);
  bf16_t* B2 = (bf16_t*)alloc((size_t)BATCH * UNITS * 2);
  bf16_t* wt = (bf16_t*)alloc((size_t)UNITS * UNITS * 2);
  float* logits = (float*)alloc((size_t)BATCH * NPAD_OUT * 4);
  bf16_t* xb = B1;  // alias: dead before block-0 iter-0 writes B1

  dim3 tb(32, 8);
  const int g_iter = (UNITS / 128) * (BATCH / 128);     // 16*32 = 512 blocks (%8==0)
  const int g_log = (NPAD_OUT / 128) * (BATCH / 128);   // 8*32 = 256 blocks (%8==0)

  // z0 = x @ W_in + b_in  -> B0 (bf16); B0 is block 0's residual base u
  k_f32_to_bf16<<<(BATCH * IN_DIM) / 256, 256, 0, stream>>>(x, xb, BATCH * IN_DIM);
  k_transpose_bf16<<<dim3(UNITS / 32, IN_DIM / 32), tb, 0, stream>>>(W_in, wt, IN_DIM, UNITS, UNITS);
  k_gemm128<0><<<g_iter, 256, 0, stream>>>(xb, wt, b_in, nullptr, B0, nullptr,
                                           BATCH, UNITS, IN_DIM, UNITS);

  // 4 blocks x NITER: y <- u + 0.1*tanh(y @ W_b + b_b); all state bf16, 3-buffer rotation
  bf16_t* ub = B0;
  for (int b = 0; b < 4; b++) {
    k_transpose_bf16<<<dim3(UNITS / 32, UNITS / 32), tb, 0, stream>>>(W[b], wt, UNITS, UNITS, UNITS);
    bf16_t* others[2];
    int k = 0;
    if (B0 != ub) others[k++] = B0;
    if (B1 != ub) others[k++] = B1;
    if (B2 != ub) others[k++] = B2;
    bf16_t* src = ub;  // y_0 = u
    for (int t = 0; t < NITER; t++) {
      bf16_t* dst = others[t & 1];
      k_gemm128<1><<<g_iter, 256, 0, stream>>>(src, wt, bb[b], ub, dst, nullptr,
                                               BATCH, UNITS, UNITS, UNITS);
      src = dst;
    }
    ub = src;  // block output becomes next block's residual base
  }

  // logits + softmax
  k_transpose_bf16<<<dim3(NPAD_OUT / 32, UNITS / 32), tb, 0, stream>>>(W_out, wt, UNITS, OUT_DIM, NPAD_OUT);
  k_gemm128<3><<<g_log, 256, 0, stream>>>(ub, wt, b_out, nullptr, nullptr, logits,
                                          BATCH, NPAD_OUT, UNITS, OUT_DIM);
  k_softmax<<<BATCH, 256, 0, stream>>>(logits, out);
}

// Round 11
// 430.429 us; speedup vs baseline: 1.4025x; 1.4025x over previous
//
#include <hip/hip_runtime.h>
#include <math.h>

#define BATCH 4096
#define IN_DIM 1024
#define UNITS 2048
#define OUT_DIM 1000
#define NPAD_OUT 1024
#define NITER 2

typedef __bf16 bf16_t;
typedef __attribute__((ext_vector_type(8))) __bf16 bfrag;
typedef __attribute__((ext_vector_type(4))) float f32x4;

typedef __attribute__((address_space(1))) void gvoid_t;
typedef __attribute__((address_space(3))) void lvoid_t;

__device__ __forceinline__ void gld_lds16(const void* g, void* l) {
  __builtin_amdgcn_global_load_lds((gvoid_t*)g, (lvoid_t*)l, 16, 0, 0);
}

// fast tanh: 1 - 2/(exp2(2*log2e*x)+1); v_exp_f32+v_rcp_f32, ~1ulp f32 (bf16-irrelevant)
__device__ __forceinline__ float fast_tanh(float x) {
  float e, r;
  asm("v_exp_f32 %0, %1" : "=v"(e) : "v"(x * 2.88539008177793f));
  asm("v_rcp_f32 %0, %1" : "=v"(r) : "v"(e + 1.0f));
  return __builtin_fmaf(-2.0f, r, 1.0f);
}

// ---------------- elementwise f32 -> bf16 ----------------
__global__ void k_f32_to_bf16(const float* __restrict__ in, bf16_t* __restrict__ out, int n) {
  int i = blockIdx.x * 256 + threadIdx.x;
  if (i < n) out[i] = (bf16_t)in[i];
}

// ---- transpose f32 (K x N, row stride N) -> bf16 (Npad x K); pads with 0 ----
__global__ void k_transpose_bf16(const float* __restrict__ src, bf16_t* __restrict__ dst,
                                 int K, int N, int Npad) {
  __shared__ float t[32][33];
  int n0 = blockIdx.x * 32;
  int k0 = blockIdx.y * 32;
  int tx = threadIdx.x, ty = threadIdx.y;  // 32 x 8
#pragma unroll
  for (int i = 0; i < 4; i++) {
    int k = k0 + ty + i * 8;
    int n = n0 + tx;
    t[ty + i * 8][tx] = (n < N) ? src[(size_t)k * N + n] : 0.0f;
  }
  __syncthreads();
#pragma unroll
  for (int i = 0; i < 4; i++) {
    int n = n0 + ty + i * 8;
    int k = k0 + tx;
    if (n < Npad) dst[(size_t)n * K + k] = (bf16_t)t[tx][ty + i * 8];
  }
}

// ======== 128^2 4-wave GEMM (m97 structure, session-verified): C = A * Bt^T ========
// 32KB LDS single buffer -> multiple independent blocks/CU; cross-block TLP overlaps
// LDS & MFMA pipes. (Round-10 A/B: explicit dbuf+counted-vmcnt was neutral -> keep simple.)
// MODE 0: Ob = bf16(acc + bias)
// MODE 1: Ob = bf16( (f32)Uin + 0.1*tanh(acc + bias) )   (all state bf16)
// MODE 3: Of = acc + bias, only cols < Nvalid (f32 logits)
template <int MODE>
__launch_bounds__(256, 2)
__global__ void k_gemm128(const bf16_t* __restrict__ A, const bf16_t* __restrict__ Bt,
                          const float* __restrict__ bias, const bf16_t* __restrict__ Uin,
                          bf16_t* __restrict__ Ob, float* __restrict__ Of,
                          int M, int N, int K, int Nvalid) {
  __shared__ bf16_t As2[128 * 64];
  __shared__ bf16_t Bs2[128 * 64];

  const int tid = threadIdx.x;
  const int lane = tid & 63;
  const int wid = tid >> 6;

  // XCD-aware bijective swizzle (grid % 8 == 0 for all our launches)
  int bid = (int)blockIdx.x;
  const int cpx = (int)gridDim.x >> 3;
  bid = (bid & 7) * cpx + (bid >> 3);
  const int nbx = N >> 7;
  const int bn0 = (bid % nbx) * 128;
  const int bm0 = (bid / nbx) * 128;

  const int srow = lane >> 3;
  const int sslot = (lane & 7) ^ srow;  // XOR swizzle via pre-swizzled global source
  const int frow = lane & 15;
  const int fk = lane >> 4;

  f32x4 acc[4][4];
#pragma unroll
  for (int m = 0; m < 4; m++)
#pragma unroll
    for (int n = 0; n < 4; n++) acc[m][n] = (f32x4){0.f, 0.f, 0.f, 0.f};

  const int wm = wid >> 1;
  const int wn = wid & 1;

  const size_t aRowBase = (size_t)(bm0 + wid * 32 + srow) * K + (size_t)sslot * 8;
  const size_t bRowBase = (size_t)(bn0 + wid * 32 + srow) * K + (size_t)sslot * 8;

  for (int kt = 0; kt < K; kt += 64) {
#pragma unroll
    for (int i = 0; i < 4; i++) {
      gld_lds16(A + aRowBase + (size_t)i * 8 * K + kt, (char*)As2 + (wid * 4 + i) * 1024);
      gld_lds16(Bt + bRowBase + (size_t)i * 8 * K + kt, (char*)Bs2 + (wid * 4 + i) * 1024);
    }
    __syncthreads();

#pragma unroll
    for (int s = 0; s < 2; s++) {
      bfrag af[4], bq[4];
#pragma unroll
      for (int m = 0; m < 4; m++) {
        int row = wm * 64 + m * 16 + frow;
        int slot = (s * 4 + fk) ^ (row & 7);
        af[m] = *reinterpret_cast<const bfrag*>((const char*)As2 + row * 128 + slot * 16);
      }
#pragma unroll
      for (int n = 0; n < 4; n++) {
        int row = wn * 64 + n * 16 + frow;
        int slot = (s * 4 + fk) ^ (row & 7);
        bq[n] = *reinterpret_cast<const bfrag*>((const char*)Bs2 + row * 128 + slot * 16);
      }
      __builtin_amdgcn_s_setprio(1);
#pragma unroll
      for (int m = 0; m < 4; m++)
#pragma unroll
        for (int n = 0; n < 4; n++)
          acc[m][n] = __builtin_amdgcn_mfma_f32_16x16x32_bf16(af[m], bq[n], acc[m][n], 0, 0, 0);
      __builtin_amdgcn_s_setprio(0);
    }
    __syncthreads();
  }

  // epilogue: C/D layout col = lane&15 (-> gn), row = (lane>>4)*4 + j (-> gm)
#pragma unroll
  for (int m = 0; m < 4; m++) {
#pragma unroll
    for (int n = 0; n < 4; n++) {
      const int gn = bn0 + wn * 64 + n * 16 + frow;
#pragma unroll
      for (int j = 0; j < 4; j++) {
        const int gm = bm0 + wm * 64 + m * 16 + fk * 4 + j;
        const size_t off = (size_t)gm * N + gn;
        float v = acc[m][n][j];
        if (MODE == 0) {
          Ob[off] = (bf16_t)(v + bias[gn]);
        } else if (MODE == 1) {
          v = (float)Uin[off] + 0.1f * fast_tanh(v + bias[gn]);
          Ob[off] = (bf16_t)v;
        } else {  // MODE 3
          if (gn < Nvalid) Of[off] = v + bias[gn];
        }
      }
    }
  }
}

// ---------------- row softmax ----------------
__global__ void k_softmax(const float* __restrict__ logits, float* __restrict__ out) {
  __shared__ float red[256];
  const int r = blockIdx.x;
  const float* L = logits + (size_t)r * NPAD_OUT;
  float* O = out + (size_t)r * OUT_DIM;
  const int tid = threadIdx.x;

  float lmax = -INFINITY;
  for (int j = tid; j < OUT_DIM; j += 256) lmax = fmaxf(lmax, L[j]);
  red[tid] = lmax;
  __syncthreads();
  for (int s = 128; s > 0; s >>= 1) {
    if (tid < s) red[tid] = fmaxf(red[tid], red[tid + s]);
    __syncthreads();
  }
  const float rmax = red[0];
  __syncthreads();
  float lsum = 0.f;
  for (int j = tid; j < OUT_DIM; j += 256) {
    float e = expf(L[j] - rmax);
    O[j] = e;
    lsum += e;
  }
  red[tid] = lsum;
  __syncthreads();
  for (int s = 128; s > 0; s >>= 1) {
    if (tid < s) red[tid] += red[tid + s];
    __syncthreads();
  }
  const float inv = 1.0f / red[0];
  for (int j = tid; j < OUT_DIM; j += 256) O[j] *= inv;
}

extern "C" void kernel_launch(void* const* d_in, const int* in_sizes, int n_in,
                              void* d_out, int out_size, void* d_ws, size_t ws_size,
                              hipStream_t stream) {
  const float* x = (const float*)d_in[0];
  const float* W_in = (const float*)d_in[1];
  const float* b_in = (const float*)d_in[2];
  const float* W_out = (const float*)d_in[3];
  const float* b_out = (const float*)d_in[4];
  const float* W[4] = {(const float*)d_in[5], (const float*)d_in[7],
                       (const float*)d_in[9], (const float*)d_in[11]};
  const float* bb[4] = {(const float*)d_in[6], (const float*)d_in[8],
                        (const float*)d_in[10], (const float*)d_in[12]};
  float* out = (float*)d_out;

  // ---- workspace: 3x16 + 8 + 16 = 72 MiB (proven-safe footprint) ----
  char* ws = (char*)d_ws;
  size_t off = 0;
  auto alloc = [&](size_t bytes) {
    void* p = ws + off;
    off += (bytes + 255) & ~(size_t)255;
    return p;
  };
  bf16_t* B0 = (bf16_t*)alloc((size_t)BATCH * UNITS * 2);
  bf16_t* B1 = (bf16_t*)alloc((size_t)BATCH * UNITS * 2);
  bf16_t* B2 = (bf16_t*)alloc((size_t)BATCH * UNITS * 2);
  bf16_t* wt = (bf16_t*)alloc((size_t)UNITS * UNITS * 2);
  float* logits = (float*)alloc((size_t)BATCH * NPAD_OUT * 4);
  bf16_t* xb = B1;  // alias: dead before block-0 iter-0 writes B1

  dim3 tb(32, 8);
  const int g_iter = (UNITS / 128) * (BATCH / 128);     // 16*32 = 512 blocks (%8==0)
  const int g_log = (NPAD_OUT / 128) * (BATCH / 128);   // 8*32 = 256 blocks (%8==0)

  // z0 = x @ W_in + b_in  -> B0 (bf16); B0 is block 0's residual base u
  k_f32_to_bf16<<<(BATCH * IN_DIM) / 256, 256, 0, stream>>>(x, xb, BATCH * IN_DIM);
  k_transpose_bf16<<<dim3(UNITS / 32, IN_DIM / 32), tb, 0, stream>>>(W_in, wt, IN_DIM, UNITS, UNITS);
  k_gemm128<0><<<g_iter, 256, 0, stream>>>(xb, wt, b_in, nullptr, B0, nullptr,
                                           BATCH, UNITS, IN_DIM, UNITS);

  // 4 blocks x NITER: y <- u + 0.1*tanh(y @ W_b + b_b); all state bf16, 3-buffer rotation
  bf16_t* ub = B0;
  for (int b = 0; b < 4; b++) {
    k_transpose_bf16<<<dim3(UNITS / 32, UNITS / 32), tb, 0, stream>>>(W[b], wt, UNITS, UNITS, UNITS);
    bf16_t* others[2];
    int k = 0;
    if (B0 != ub) others[k++] = B0;
    if (B1 != ub) others[k++] = B1;
    if (B2 != ub) others[k++] = B2;
    bf16_t* src = ub;  // y_0 = u
    for (int t = 0; t < NITER; t++) {
      bf16_t* dst = others[t & 1];
      k_gemm128<1><<<g_iter, 256, 0, stream>>>(src, wt, bb[b], ub, dst, nullptr,
                                               BATCH, UNITS, UNITS, UNITS);
      src = dst;
    }
    ub = src;  // block output becomes next block's residual base
  }

  // logits + softmax
  k_transpose_bf16<<<dim3(NPAD_OUT / 32, UNITS / 32), tb, 0, stream>>>(W_out, wt, UNITS, OUT_DIM, NPAD_OUT);
  k_gemm128<3><<<g_log, 256, 0, stream>>>(ub, wt, b_out, nullptr, nullptr, logits,
                                          BATCH, NPAD_OUT, UNITS, OUT_DIM);
  k_softmax<<<BATCH, 256, 0, stream>>>(logits, out);
}